// Round 10
// baseline (172.223 us; speedup 1.0000x reference)
//
#include <hip/hip_runtime.h>
#include <hip/hip_bf16.h>
#include <math.h>

#define B_  2
#define T_  2048
#define D_  1024
#define H_  16
#define HD_ 64

typedef __attribute__((ext_vector_type(8))) short short8;
typedef __attribute__((ext_vector_type(4))) float f32x4;

#if __has_builtin(__builtin_amdgcn_exp2f)
#define EXP2F __builtin_amdgcn_exp2f
#else
#define EXP2F exp2f
#endif

__device__ __forceinline__ ushort f2bf(float x) {
    unsigned u = __builtin_bit_cast(unsigned, x);
    return (ushort)((u + 0x7FFFu + ((u >> 16) & 1u)) >> 16);  // RTNE
}

// round-half-up bf16 pair pack
__device__ __forceinline__ unsigned pack_bf2_fast(float a, float b) {
    unsigned ua = __builtin_bit_cast(unsigned, a) + 0x8000u;
    unsigned ub = __builtin_bit_cast(unsigned, b) + 0x8000u;
    return (ua >> 16) | (ub & 0xFFFF0000u);
}

__device__ __forceinline__ void load_lds_16B(const ushort* g, ushort* l) {
    __builtin_amdgcn_global_load_lds(
        (const __attribute__((address_space(1))) unsigned*)g,
        (__attribute__((address_space(3))) unsigned*)l, 16, 0, 0);
}

// ---------------------------------------------------------------------------
// Merged prep: [0,512) cast x->bf16; [512,1280) transpose Wqkv; [1280,1536)
// transpose Wout. Wt stores are 16B/lane.
// ---------------------------------------------------------------------------
__global__ __launch_bounds__(256)
void prep_kernel(const float* __restrict__ x, ushort* __restrict__ xb,
                 const float* __restrict__ Wqkv, ushort* __restrict__ Wqkvt,
                 const float* __restrict__ Wout, ushort* __restrict__ Woutt)
{
    __shared__ ushort Ts[64][65];
    const int bid = blockIdx.x;

    if (bid < 512) {
        const int n4 = (B_ * T_ * D_) / 4;
        for (int i = bid * 256 + threadIdx.x; i < n4; i += 512 * 256) {
            float4 v = ((const float4*)x)[i];
            ushort4 o = { f2bf(v.x), f2bf(v.y), f2bf(v.z), f2bf(v.w) };
            ((ushort4*)xb)[i] = o;
        }
        return;
    }

    const float* W; ushort* Wt; int K, M, m0, k0;
    if (bid < 1280) {
        const int t = bid - 512;
        W = Wqkv; Wt = Wqkvt; K = D_; M = 3 * D_;
        m0 = (t % 48) * 64; k0 = (t / 48) * 64;
    } else {
        const int t = bid - 1280;
        W = Wout; Wt = Woutt; K = D_; M = D_;
        m0 = (t % 16) * 64; k0 = (t / 16) * 64;
    }

    const int tr = threadIdx.x >> 4;
    const int tc = threadIdx.x & 15;
    #pragma unroll
    for (int it = 0; it < 4; it++) {
        int k = tr + it * 16;
        float4 v = *(const float4*)&W[(size_t)(k0 + k) * M + m0 + tc * 4];
        Ts[tc * 4 + 0][k] = f2bf(v.x);
        Ts[tc * 4 + 1][k] = f2bf(v.y);
        Ts[tc * 4 + 2][k] = f2bf(v.z);
        Ts[tc * 4 + 3][k] = f2bf(v.w);
    }
    __syncthreads();
    #pragma unroll
    for (int it = 0; it < 2; it++) {
        const int mr  = (threadIdx.x >> 3) + it * 32;
        const int seg = (threadIdx.x & 7) * 8;
        short8 v;
        #pragma unroll
        for (int r = 0; r < 8; r++) v[r] = (short)Ts[mr][seg + r];
        *(short8*)&Wt[(size_t)(m0 + mr) * K + k0 + seg] = v;
    }
}

// ---------------------------------------------------------------------------
// QKV GEMM (round-9 known-good): 128x128 tile, coalesced LDS-staged epilogue.
// ---------------------------------------------------------------------------
__global__ __launch_bounds__(256, 4)
void gemm_qkv(const ushort* __restrict__ A, const ushort* __restrict__ Bt,
              const float* __restrict__ bias,
              ushort* __restrict__ Qg, ushort* __restrict__ Kg,
              ushort* __restrict__ Vtg)
{
    const int K = D_;
    __shared__ __align__(16) ushort lds[16384];
    ushort* Asl = lds;
    ushort* Bsl = lds + 8192;

    const int tid = threadIdx.x;
    const int w  = tid >> 6, L = tid & 63;
    const int lt = L & 15, lq = L >> 4;
    const int wr = w >> 1, wc = w & 1;
    const int m0 = blockIdx.x * 128, n0 = blockIdx.y * 128;
    const int rsub = L >> 3;
    const int pgr  = L & 7;

    f32x4 acc[4][4] = {};

    for (int k0 = 0; k0 < K; k0 += 64) {
        __syncthreads();
        #pragma unroll
        for (int j = 0; j < 4; j++) {
            const int row  = (w * 4 + j) * 8 + rsub;
            const int gran = pgr ^ rsub;
            load_lds_16B(A  + (size_t)(n0 + row) * K + k0 + gran * 8,
                         &Asl[row * 64 + pgr * 8]);
            load_lds_16B(Bt + (size_t)(m0 + row) * K + k0 + gran * 8,
                         &Bsl[row * 64 + pgr * 8]);
        }
        __syncthreads();

        #pragma unroll
        for (int ks = 0; ks < 2; ks++) {
            short8 af[4], bf[4];
            #pragma unroll
            for (int i = 0; i < 4; i++) {
                const int ra = wr * 64 + i * 16 + lt;
                af[i] = *(const short8*)&Asl[ra * 64 + (((ks * 4 + lq) ^ (ra & 7)) * 8)];
                const int rb = wc * 64 + i * 16 + lt;
                bf[i] = *(const short8*)&Bsl[rb * 64 + (((ks * 4 + lq) ^ (rb & 7)) * 8)];
            }
            #pragma unroll
            for (int i = 0; i < 4; i++)
                #pragma unroll
                for (int j = 0; j < 4; j++)
                    acc[i][j] = __builtin_amdgcn_mfma_f32_16x16x32_bf16(af[i], bf[j], acc[i][j], 0, 0, 0);
        }
    }

    __syncthreads();
    const int s  = m0 >> 10;
    const int h0 = (m0 & 1023) >> 6;
    const float qs = (s == 0) ? 0.18033688011112042f : 1.0f;   // 0.125*log2(e)

    if (s < 2) {
        #pragma unroll
        for (int j = 0; j < 4; j++) {
            const int m  = wc * 64 + j * 16 + lt;
            const float bv = bias[m0 + m];
            #pragma unroll
            for (int i = 0; i < 4; i++) {
                const int n = wr * 64 + i * 16 + lq * 4;
                #pragma unroll
                for (int r = 0; r < 4; r++)
                    lds[(n + r) * 128 + m] = f2bf((acc[i][j][r] + bv) * qs);
            }
        }
        __syncthreads();
        ushort* dst = (s == 0 ? Qg : Kg);
        #pragma unroll
        for (int it = 0; it < 8; it++) {
            const int g   = tid + it * 256;
            const int row = g >> 4, c = g & 15;
            const int n = n0 + row;
            const int b = n >> 11, t = n & 2047;
            const int h = h0 + (c >> 3), d = (c & 7) * 8;
            short8 v = *(const short8*)&lds[row * 128 + c * 8];
            *(short8*)&dst[((size_t)(b * H_ + h) * T_ + t) * HD_ + d] = v;
        }
    } else {
        #pragma unroll
        for (int j = 0; j < 4; j++) {
            const int m  = wc * 64 + j * 16 + lt;
            const float bv = bias[m0 + m];
            #pragma unroll
            for (int i = 0; i < 4; i++) {
                const int n = wr * 64 + i * 16 + lq * 4;
                uint2 pk = { pack_bf2_fast(acc[i][j][0] + bv, acc[i][j][1] + bv),
                             pack_bf2_fast(acc[i][j][2] + bv, acc[i][j][3] + bv) };
                *(uint2*)&lds[m * 128 + n] = pk;
            }
        }
        __syncthreads();
        const int b = n0 >> 11, t0 = n0 & 2047;
        #pragma unroll
        for (int it = 0; it < 8; it++) {
            const int g   = tid + it * 256;
            const int row = g >> 4, c = g & 15;
            const int h = h0 + (row >> 6), d = row & 63;
            short8 v = *(const short8*)&lds[row * 128 + c * 8];
            *(short8*)&Vtg[((size_t)(b * H_ + h) * HD_ + d) * T_ + t0 + c * 8] = v;
        }
    }
}

// ---------------------------------------------------------------------------
// Out GEMM (round-9 known-good): swapped operands, direct float4 stores.
// ---------------------------------------------------------------------------
__global__ __launch_bounds__(256, 4)
void gemm_out(const ushort* __restrict__ A, const ushort* __restrict__ Bt,
              const float* __restrict__ bias, float* __restrict__ C)
{
    const int K = D_, M = D_;
    __shared__ __align__(16) ushort lds[8192 + 4096];
    ushort* Asl = lds;
    ushort* Bsl = lds + 8192;

    const int tid = threadIdx.x;
    const int w  = tid >> 6, L = tid & 63;
    const int lt = L & 15, lq = L >> 4;
    const int wr = w >> 1, wc = w & 1;
    const int m0 = blockIdx.x * 64, n0 = blockIdx.y * 128;
    const int rsub = L >> 3;
    const int pgr  = L & 7;

    f32x4 acc[2][4] = {};

    for (int k0 = 0; k0 < K; k0 += 64) {
        __syncthreads();
        #pragma unroll
        for (int j = 0; j < 4; j++) {
            const int row  = (w * 4 + j) * 8 + rsub;
            const int gran = pgr ^ rsub;
            load_lds_16B(A + (size_t)(n0 + row) * K + k0 + gran * 8,
                         &Asl[row * 64 + pgr * 8]);
        }
        #pragma unroll
        for (int j = 0; j < 2; j++) {
            const int row  = (w * 2 + j) * 8 + rsub;
            const int gran = pgr ^ rsub;
            load_lds_16B(Bt + (size_t)(m0 + row) * K + k0 + gran * 8,
                         &Bsl[row * 64 + pgr * 8]);
        }
        __syncthreads();

        #pragma unroll
        for (int ks = 0; ks < 2; ks++) {
            short8 wf[2], yf[4];
            #pragma unroll
            for (int j = 0; j < 2; j++) {
                const int rb = wc * 32 + j * 16 + lt;
                wf[j] = *(const short8*)&Bsl[rb * 64 + (((ks * 4 + lq) ^ (rb & 7)) * 8)];
            }
            #pragma unroll
            for (int i = 0; i < 4; i++) {
                const int ra = wr * 64 + i * 16 + lt;
                yf[i] = *(const short8*)&Asl[ra * 64 + (((ks * 4 + lq) ^ (ra & 7)) * 8)];
            }
            #pragma unroll
            for (int j = 0; j < 2; j++)
                #pragma unroll
                for (int i = 0; i < 4; i++)
                    acc[j][i] = __builtin_amdgcn_mfma_f32_16x16x32_bf16(wf[j], yf[i], acc[j][i], 0, 0, 0);
        }
    }

    #pragma unroll
    for (int j = 0; j < 2; j++) {
        const int mbase = m0 + wc * 32 + j * 16 + lq * 4;
        const float4 bv = *(const float4*)&bias[mbase];
        #pragma unroll
        for (int i = 0; i < 4; i++) {
            const int n = n0 + wr * 64 + i * 16 + lt;
            float4 o = { acc[j][i][0] + bv.x, acc[j][i][1] + bv.y,
                         acc[j][i][2] + bv.z, acc[j][i][3] + bv.w };
            *(float4*)&C[(size_t)n * M + mbase] = o;
        }
    }
}

// ---------------------------------------------------------------------------
// MFMA flash attention v6: 128 q-rows per block (each wave owns TWO 16-row
// subtiles) -> K/V staging and fragment reads amortized over 2x MFMA.
// Grid (16,16,2) = 512 blocks; co-resident CU pair = (z=0,z=1) -> Qt =
// z ? x : 15-x gives every CU exactly 17 kb-iterations. Ps double-buffered
// by chunk parity so chunk j+1 QK/exp can interleave with chunk j PV.
// ---------------------------------------------------------------------------
__global__ __launch_bounds__(256, 2)
void attn_mfma(const ushort* __restrict__ Qg, const ushort* __restrict__ Kg,
               const ushort* __restrict__ Vtg, ushort* __restrict__ yb)
{
    const int h = blockIdx.y, b = blockIdx.z;
    const int Qt = blockIdx.z ? blockIdx.x : (15 - blockIdx.x);
    const int tid = threadIdx.x;
    const int w  = tid >> 6, L = tid & 63;
    const int lt = L & 15, lq = L >> 4;
    const int kswz = lt & 7;

    __shared__ __align__(16) ushort Ks [128 * 64];        // 16 KB
    __shared__ __align__(16) ushort Vts[64 * 128];        // 16 KB
    __shared__ __align__(16) ushort Ps [4][2][2][640];    // 20 KB [wave][sub][parity]

    const size_t bh = (size_t)(b * H_ + h);
    const ushort* Qbase  = Qg  + bh * T_ * HD_;
    const ushort* Kbase  = Kg  + bh * T_ * HD_;
    const ushort* Vtbase = Vtg + bh * HD_ * T_;

    // wave owns q rows [Qt*128 + w*32, +32): subtiles s=0,1 (16 rows each)
    short8 qf[2][2];
    #pragma unroll
    for (int s = 0; s < 2; s++) {
        const int row = Qt * 128 + w * 32 + s * 16 + lt;
        qf[s][0] = *(const short8*)(Qbase + (size_t)row * HD_ + lq * 8);
        qf[s][1] = *(const short8*)(Qbase + (size_t)row * HD_ + 32 + lq * 8);
    }

    f32x4 acc_o[2][4] = {};
    float lsum[2] = {0.f, 0.f};

    const int krow = tid >> 3, kpg = tid & 7;
    const int vrow = tid >> 4, vpg = tid & 15;
    const int nk = Qt + 1;

    for (int kb = 0; kb < nk; kb++) {
        __syncthreads();
        #pragma unroll
        for (int rr = 0; rr < 4; rr++) {
            const int row = krow + 32 * rr;
            load_lds_16B(Kbase + (size_t)(kb * 128 + row) * HD_ + (kpg ^ (row & 7)) * 8,
                         &Ks[row * 64 + kpg * 8]);
        }
        #pragma unroll
        for (int rr = 0; rr < 4; rr++) {
            const int d = vrow + 16 * rr;
            load_lds_16B(Vtbase + (size_t)d * T_ + kb * 128 + (vpg ^ (d & 7)) * 8,
                         &Vts[d * 128 + vpg * 8]);
        }
        __syncthreads();

        if (kb < nk - 1) {
            // ---------------- hot path: both subtiles, no masking ----------------
            #pragma unroll
            for (int ks = 0; ks < 4; ks++) {
                const int row0 = (2 * ks) * 16 + lt;
                const int row1 = row0 + 16;
                short8 a00 = *(const short8*)&Ks[row0 * 64 + ((lq ^ kswz) * 8)];
                short8 a01 = *(const short8*)&Ks[row0 * 64 + (((4 + lq) ^ kswz) * 8)];
                short8 a10 = *(const short8*)&Ks[row1 * 64 + ((lq ^ kswz) * 8)];
                short8 a11 = *(const short8*)&Ks[row1 * 64 + (((4 + lq) ^ kswz) * 8)];
                f32x4 c00 = {}, c01 = {}, c10 = {}, c11 = {};
                c00 = __builtin_amdgcn_mfma_f32_16x16x32_bf16(a00, qf[0][0], c00, 0, 0, 0);
                c00 = __builtin_amdgcn_mfma_f32_16x16x32_bf16(a01, qf[0][1], c00, 0, 0, 0);
                c01 = __builtin_amdgcn_mfma_f32_16x16x32_bf16(a10, qf[0][0], c01, 0, 0, 0);
                c01 = __builtin_amdgcn_mfma_f32_16x16x32_bf16(a11, qf[0][1], c01, 0, 0, 0);
                c10 = __builtin_amdgcn_mfma_f32_16x16x32_bf16(a00, qf[1][0], c10, 0, 0, 0);
                c10 = __builtin_amdgcn_mfma_f32_16x16x32_bf16(a01, qf[1][1], c10, 0, 0, 0);
                c11 = __builtin_amdgcn_mfma_f32_16x16x32_bf16(a10, qf[1][0], c11, 0, 0, 0);
                c11 = __builtin_amdgcn_mfma_f32_16x16x32_bf16(a11, qf[1][1], c11, 0, 0, 0);

                float p0 = EXP2F(c00[0]), p1 = EXP2F(c00[1]), p2 = EXP2F(c00[2]), p3 = EXP2F(c00[3]);
                float p4 = EXP2F(c01[0]), p5 = EXP2F(c01[1]), p6 = EXP2F(c01[2]), p7 = EXP2F(c01[3]);
                lsum[0] += ((p0 + p1) + (p2 + p3)) + ((p4 + p5) + (p6 + p7));
                *(uint2*)&Ps[w][0][ks & 1][lt * 40 + lq * 4] =
                    (uint2){ pack_bf2_fast(p0, p1), pack_bf2_fast(p2, p3) };
                *(uint2*)&Ps[w][0][ks & 1][lt * 40 + 16 + lq * 4] =
                    (uint2){ pack_bf2_fast(p4, p5), pack_bf2_fast(p6, p7) };

                float r0 = EXP2F(c10[0]), r1 = EXP2F(c10[1]), r2 = EXP2F(c10[2]), r3 = EXP2F(c10[3]);
                float r4 = EXP2F(c11[0]), r5 = EXP2F(c11[1]), r6 = EXP2F(c11[2]), r7 = EXP2F(c11[3]);
                lsum[1] += ((r0 + r1) + (r2 + r3)) + ((r4 + r5) + (r6 + r7));
                *(uint2*)&Ps[w][1][ks & 1][lt * 40 + lq * 4] =
                    (uint2){ pack_bf2_fast(r0, r1), pack_bf2_fast(r2, r3) };
                *(uint2*)&Ps[w][1][ks & 1][lt * 40 + 16 + lq * 4] =
                    (uint2){ pack_bf2_fast(r4, r5), pack_bf2_fast(r6, r7) };

                short8 pf0 = *(const short8*)&Ps[w][0][ks & 1][lt * 40 + lq * 8];
                short8 pf1 = *(const short8*)&Ps[w][1][ks & 1][lt * 40 + lq * 8];

                #pragma unroll
                for (int dt = 0; dt < 4; dt++) {
                    const int vr = dt * 16 + lt;
                    short8 vf = *(const short8*)&Vts[vr * 128 + (((ks * 4 + lq) ^ kswz) * 8)];
                    acc_o[0][dt] = __builtin_amdgcn_mfma_f32_16x16x32_bf16(pf0, vf, acc_o[0][dt], 0, 0, 0);
                    acc_o[1][dt] = __builtin_amdgcn_mfma_f32_16x16x32_bf16(pf1, vf, acc_o[1][dt], 0, 0, 0);
                }
            }
        } else {
            // -------- final kb: per-subtile chunk counts + causal masking --------
            #pragma unroll
            for (int s = 0; s < 2; s++) {
                const int row_base = w * 32 + s * 16;      // in-tile q base
                const int mk  = row_base >> 5;             // first masked chunk
                const int ksN = (row_base + 47) >> 5;      // chunks to process
                const int q_in = row_base + lt;            // in-tile q row
                for (int ks = 0; ks < ksN; ks++) {
                    const int row0 = (2 * ks) * 16 + lt;
                    const int row1 = row0 + 16;
                    short8 a00 = *(const short8*)&Ks[row0 * 64 + ((lq ^ kswz) * 8)];
                    short8 a01 = *(const short8*)&Ks[row0 * 64 + (((4 + lq) ^ kswz) * 8)];
                    short8 a10 = *(const short8*)&Ks[row1 * 64 + ((lq ^ kswz) * 8)];
                    short8 a11 = *(const short8*)&Ks[row1 * 64 + (((4 + lq) ^ kswz) * 8)];
                    f32x4 c0 = {}, c1 = {};
                    c0 = __builtin_amdgcn_mfma_f32_16x16x32_bf16(a00, qf[s][0], c0, 0, 0, 0);
                    c0 = __builtin_amdgcn_mfma_f32_16x16x32_bf16(a01, qf[s][1], c0, 0, 0, 0);
                    c1 = __builtin_amdgcn_mfma_f32_16x16x32_bf16(a10, qf[s][0], c1, 0, 0, 0);
                    c1 = __builtin_amdgcn_mfma_f32_16x16x32_bf16(a11, qf[s][1], c1, 0, 0, 0);

                    float p[8];
                    #pragma unroll
                    for (int r = 0; r < 4; r++) { p[r] = EXP2F(c0[r]); p[4 + r] = EXP2F(c1[r]); }
                    if (ks >= mk) {
                        const int key0 = ks * 32 + lq * 4;  // in-tile key
                        #pragma unroll
                        for (int r = 0; r < 4; r++) {
                            if (key0 + r > q_in)      p[r] = 0.f;
                            if (key0 + 16 + r > q_in) p[4 + r] = 0.f;
                        }
                    }
                    lsum[s] += ((p[0] + p[1]) + (p[2] + p[3])) + ((p[4] + p[5]) + (p[6] + p[7]));
                    *(uint2*)&Ps[w][s][ks & 1][lt * 40 + lq * 4] =
                        (uint2){ pack_bf2_fast(p[0], p[1]), pack_bf2_fast(p[2], p[3]) };
                    *(uint2*)&Ps[w][s][ks & 1][lt * 40 + 16 + lq * 4] =
                        (uint2){ pack_bf2_fast(p[4], p[5]), pack_bf2_fast(p[6], p[7]) };

                    short8 pf = *(const short8*)&Ps[w][s][ks & 1][lt * 40 + lq * 8];

                    #pragma unroll
                    for (int dt = 0; dt < 4; dt++) {
                        const int vr = dt * 16 + lt;
                        short8 vf = *(const short8*)&Vts[vr * 128 + (((ks * 4 + lq) ^ kswz) * 8)];
                        acc_o[s][dt] = __builtin_amdgcn_mfma_f32_16x16x32_bf16(pf, vf, acc_o[s][dt], 0, 0, 0);
                    }
                }
            }
        }
    }

    // ---- epilogue per subtile: reduce lsum across lq lanes, write bf16 y ----
    #pragma unroll
    for (int s = 0; s < 2; s++) {
        float ls = lsum[s];
        ls += __shfl_xor(ls, 16, 64);
        ls += __shfl_xor(ls, 32, 64);
        const float inv = 1.0f / ls;

        float linv[4];
        #pragma unroll
        for (int r = 0; r < 4; r++) linv[r] = __shfl(inv, lq * 4 + r, 64);

        ushort* ybase = yb + (size_t)(b * T_ + Qt * 128 + w * 32 + s * 16) * D_ + h * HD_;
        #pragma unroll
        for (int r = 0; r < 4; r++)
            #pragma unroll
            for (int dt = 0; dt < 4; dt++)
                ybase[(size_t)(lq * 4 + r) * D_ + dt * 16 + lt] = f2bf(acc_o[s][dt][r] * linv[r]);
    }
}

// ---------------------------------------------------------------------------
extern "C" void kernel_launch(void* const* d_in, const int* in_sizes, int n_in,
                              void* d_out, int out_size, void* d_ws, size_t ws_size,
                              hipStream_t stream)
{
    const float* x    = (const float*)d_in[0];
    const float* Wqkv = (const float*)d_in[1];
    const float* bqkv = (const float*)d_in[2];
    const float* Wout = (const float*)d_in[3];
    const float* bout = (const float*)d_in[4];
    float* out = (float*)d_out;

    char* ws = (char*)d_ws;
    const size_t NT = (size_t)B_ * T_;
    ushort* xb     = (ushort*)ws;
    ushort* Wqkvt  = (ushort*)(ws + NT * D_ * 2);
    ushort* Woutt  = (ushort*)(ws + NT * D_ * 2 + (size_t)3 * D_ * D_ * 2);
    char*   p      = ws + NT * D_ * 2 + (size_t)4 * D_ * D_ * 2;
    const size_t qkv_elems = (size_t)B_ * H_ * T_ * HD_;
    ushort* Qg  = (ushort*)p;
    ushort* Kg  = (ushort*)(p + qkv_elems * 2);
    ushort* Vtg = (ushort*)(p + qkv_elems * 4);
    ushort* yb  = (ushort*)(p + qkv_elems * 6);

    prep_kernel<<<1536, 256, 0, stream>>>(x, xb, Wqkv, Wqkvt, Wout, Woutt);

    gemm_qkv<<<dim3(3 * D_ / 128, NT / 128), 256, 0, stream>>>(
        xb, Wqkvt, bqkv, Qg, Kg, Vtg);

    attn_mfma<<<dim3(16, H_, B_), 256, 0, stream>>>(Qg, Kg, Vtg, yb);

    gemm_out<<<dim3(D_ / 64, NT / 128), 256, 0, stream>>>(
        yb, Woutt, bout, out);
}